// Round 2
// baseline (209.592 us; speedup 1.0000x reference)
//
#include <hip/hip_runtime.h>
#include <hip/hip_bf16.h>
#include <cstdint>

// ---------------------------------------------------------------------------
// GAT forward, N=4096, F=512, D=64, H=8, O=128, fp32 in/out.
//   adj -> bitmask (2MB, L2-resident)
//   gemm1 (bf16 MFMA): writes VT1 = (x@Wcat)^T bf16 AND s1/s2 row-dots
//   agg:  P generated in-register from rank-1 logits (+ adjacency bit),
//         A=P bf16, B=Wh^T, mfma 16x16x32; Z via extra MFMA vs ones-column.
//         RT=2 rows-tiles/wave, jz-split for occupancy; bf16 partial slices.
//   fin1: ELU(H/Z) -> hcat bf16 ; gemm2 split-K + combine (VT2, s1o/s2o)
//   agg2, fin2 -> out.
// No softmax max-subtraction needed: |logit| small; masked -> p=0 exactly.
// ---------------------------------------------------------------------------

using bf16_t = __bf16;
using bf16x4 = __attribute__((ext_vector_type(4))) __bf16;
using bf16x8 = __attribute__((ext_vector_type(8))) __bf16;
using f32x4  = __attribute__((ext_vector_type(4))) float;

#define LOG2E 1.44269504f
constexpr int NN = 4096;

// ---- pack adjacency into bitmask: bit j of word [i][j/32] = (adj[i][j] > 0)
__global__ __launch_bounds__(256) void pack_bits_k(const int* __restrict__ adj,
                                                   uint32_t* __restrict__ bits, int total) {
    int stride = gridDim.x * blockDim.x;
    for (int idx = blockIdx.x * blockDim.x + threadIdx.x; idx < total; idx += stride) {
        unsigned long long m = __ballot(adj[idx] > 0);
        int l = threadIdx.x & 63;
        if (l == 0)        bits[idx >> 5] = (uint32_t)m;
        else if (l == 32)  bits[idx >> 5] = (uint32_t)(m >> 32);
    }
}

// ---- prep: x->bf16, W_heads [H][F][D] -> WT1[(h*64+d)][F], W_out -> WoutT[o][512]
__global__ __launch_bounds__(256) void prep_k(const float* __restrict__ x,
                                              const float* __restrict__ Wh,
                                              const float* __restrict__ Wo,
                                              bf16_t* __restrict__ xb,
                                              bf16_t* __restrict__ WT1,
                                              bf16_t* __restrict__ WoutT) {
    const int NX = NN * 512, NW1 = 512 * 512, NW2 = 128 * 512;
    int stride = gridDim.x * blockDim.x;
    for (int t = blockIdx.x * blockDim.x + threadIdx.x; t < NX + NW1 + NW2; t += stride) {
        if (t < NX) {
            xb[t] = (bf16_t)x[t];
        } else if (t < NX + NW1) {
            int u = t - NX; int hd = u >> 9, f = u & 511; int h = hd >> 6, d = hd & 63;
            WT1[u] = (bf16_t)Wh[(h << 15) + (f << 6) + d];
        } else {
            int u = t - NX - NW1; int o = u >> 9, cc = u & 511;
            WoutT[u] = (bf16_t)Wo[cc * 128 + o];
        }
    }
}

// ---- bf16 MFMA GEMM, wave = 16 rows x 64 cols.
// CS: epilogue writes VT (bf16 transposed) + s1/s2 row-dots (per-head, cb=head*64)
// WC: writes fp32 partial C slice (split-K via blockIdx.z)
template<int CS, int WC>
__global__ __launch_bounds__(64) void gemm_k(const bf16_t* __restrict__ A,
                                             const bf16_t* __restrict__ BT,
                                             bf16_t* __restrict__ VTo,
                                             float* __restrict__ Cp,
                                             const float* __restrict__ a1,
                                             const float* __restrict__ a2,
                                             float* __restrict__ s1,
                                             float* __restrict__ s2,
                                             int K, int NC, int kslice) {
    const int lane = threadIdx.x, lr = lane & 15, kg = lane >> 4;
    const int rowb = blockIdx.x * 16, cb = blockIdx.y * 64, kz = blockIdx.z;
    f32x4 acc[4];
#pragma unroll
    for (int dt = 0; dt < 4; ++dt) acc[dt] = 0.0f;
    const bf16_t* Ap = A + (size_t)(rowb + lr) * K;
    const int k0beg = kz * kslice, k0end = k0beg + kslice;
    for (int k0 = k0beg; k0 < k0end; k0 += 32) {
        bf16x8 af = *(const bf16x8*)(Ap + k0 + kg * 8);
#pragma unroll
        for (int dt = 0; dt < 4; ++dt) {
            bf16x8 bfr = *(const bf16x8*)(BT + (size_t)(cb + dt * 16 + lr) * K + k0 + kg * 8);
            acc[dt] = __builtin_amdgcn_mfma_f32_16x16x32_bf16(af, bfr, acc[dt], 0, 0, 0);
        }
    }
    if (WC) {
#pragma unroll
        for (int dt = 0; dt < 4; ++dt)
#pragma unroll
            for (int r = 0; r < 4; ++r)
                Cp[((size_t)kz * NN + rowb + kg * 4 + r) * NC + cb + dt * 16 + lr] = acc[dt][r];
    }
    if (CS) {
#pragma unroll
        for (int dt = 0; dt < 4; ++dt) {
            bf16x4 v;
#pragma unroll
            for (int r = 0; r < 4; ++r) v[r] = (bf16_t)acc[dt][r];
            *(bf16x4*)(VTo + (size_t)(cb + dt * 16 + lr) * NN + rowb + kg * 4) = v;
        }
        float a1v[4], a2v[4];
#pragma unroll
        for (int dt = 0; dt < 4; ++dt) {
            a1v[dt] = a1[cb + dt * 16 + lr];
            a2v[dt] = a2[cb + dt * 16 + lr];
        }
#pragma unroll
        for (int r = 0; r < 4; ++r) {
            float d1 = 0.f, d2 = 0.f;
#pragma unroll
            for (int dt = 0; dt < 4; ++dt) { d1 += acc[dt][r] * a1v[dt]; d2 += acc[dt][r] * a2v[dt]; }
#pragma unroll
            for (int o = 1; o < 16; o <<= 1) { d1 += __shfl_xor(d1, o); d2 += __shfl_xor(d2, o); }
            if (lr == 0) {
                s1[(size_t)blockIdx.y * NN + rowb + kg * 4 + r] = d1 * LOG2E;
                s2[(size_t)blockIdx.y * NN + rowb + kg * 4 + r] = d2 * LOG2E;
            }
        }
    }
}

// ---- fused attention-aggregate: wave = 32 rows x 64 cols (colgrp c), j-range jz.
// Hpart[jz] (bf16) = P*V partial; zpart[zi] = row sums of P via MFMA ones-column.
__global__ __launch_bounds__(64, 4) void gat_agg_k(const float* __restrict__ s1,
                                                   const float* __restrict__ s2, int shead,
                                                   const uint32_t* __restrict__ bits,
                                                   const bf16_t* __restrict__ VT,
                                                   bf16_t* __restrict__ Hpart,
                                                   float* __restrict__ zpart,
                                                   int CT, int JR, int ZC) {
    const int lane = threadIdx.x, lr = lane & 15, kg = lane >> 4;
    const int rowb = blockIdx.x * 32, c = blockIdx.y, jz = blockIdx.z;
    const int cb = c * 64;
    const float* s1p = s1 + (size_t)shead * c;
    const float* s2p = s2 + (size_t)shead * c;
    const int steps = JR >> 5, jb0 = jz * JR;

    f32x4 acc[2][4], accz[2];
#pragma unroll
    for (int rt = 0; rt < 2; ++rt) {
        accz[rt] = 0.0f;
#pragma unroll
        for (int dt = 0; dt < 4; ++dt) acc[rt][dt] = 0.0f;
    }
    float s1v[2]; int rows[2];
#pragma unroll
    for (int rt = 0; rt < 2; ++rt) {
        rows[rt] = rowb + rt * 16 + lr;
        s1v[rt] = s1p[rows[rt]];
    }
    bf16x8 ones;
#pragma unroll
    for (int e = 0; e < 8; ++e) ones[e] = (bf16_t)(lr == 0 ? 1.0f : 0.0f);

    for (int js = 0; js < steps; ++js) {
        const int jb = jb0 + js * 32, jk = jb + kg * 8;
        f32x4 s2a = *(const f32x4*)(s2p + jk);
        f32x4 s2b = *(const f32x4*)(s2p + jk + 4);
        bf16x8 bfr[4];
#pragma unroll
        for (int dt = 0; dt < 4; ++dt)
            bfr[dt] = *(const bf16x8*)(VT + (size_t)(cb + dt * 16 + lr) * NN + jk);
#pragma unroll
        for (int rt = 0; rt < 2; ++rt) {
            uint32_t w = bits[(size_t)rows[rt] * (NN / 32) + (jb >> 5)];
            uint32_t mb = (w >> (kg * 8)) & 0xffu;
            bf16x8 af;
#pragma unroll
            for (int e = 0; e < 8; ++e) {
                float s2v = (e < 4) ? s2a[e] : s2b[e - 4];
                float u = s1v[rt] + s2v;          // log2e-scaled logit
                float m = fmaxf(u, 0.2f * u);     // leakyrelu
                float p = exp2f(m);
                p = (mb & (1u << e)) ? p : 0.0f;
                af[e] = (bf16_t)p;
            }
#pragma unroll
            for (int dt = 0; dt < 4; ++dt)
                acc[rt][dt] = __builtin_amdgcn_mfma_f32_16x16x32_bf16(af, bfr[dt], acc[rt][dt], 0, 0, 0);
            accz[rt] = __builtin_amdgcn_mfma_f32_16x16x32_bf16(af, ones, accz[rt], 0, 0, 0);
        }
    }

    bf16_t* Hp = Hpart + (size_t)jz * NN * CT;
#pragma unroll
    for (int rt = 0; rt < 2; ++rt)
#pragma unroll
        for (int dt = 0; dt < 4; ++dt)
#pragma unroll
            for (int r = 0; r < 4; ++r)
                Hp[(size_t)(rowb + rt * 16 + kg * 4 + r) * CT + cb + dt * 16 + lr] = (bf16_t)acc[rt][dt][r];
    if (lr == 0 && (ZC > 1 || c == 0)) {
        int zi = jz * ZC + (ZC > 1 ? c : 0);
#pragma unroll
        for (int rt = 0; rt < 2; ++rt)
#pragma unroll
            for (int r = 0; r < 4; ++r)
                zpart[(size_t)zi * NN + rowb + rt * 16 + kg * 4 + r] = accz[rt][r];
    }
}

// ---- finalize layer 1: hcatb = bf16(ELU(sum H / sum Z)), 8 cols/thread
__global__ __launch_bounds__(256) void fin1_k(const bf16_t* __restrict__ Hpart,
                                              const float* __restrict__ zpart,
                                              bf16_t* __restrict__ hcatb) {
    int idx = blockIdx.x * 256 + threadIdx.x;   // < N*64
    int i = idx >> 6, col0 = (idx & 63) << 3, h = col0 >> 6;
    float Z = 0.f;
#pragma unroll
    for (int jz = 0; jz < 8; ++jz) Z += zpart[(size_t)(jz * 8 + h) * NN + i];
    float hs[8];
#pragma unroll
    for (int e = 0; e < 8; ++e) hs[e] = 0.f;
#pragma unroll
    for (int jz = 0; jz < 8; ++jz) {
        bf16x8 v = *(const bf16x8*)(Hpart + ((size_t)jz * NN + i) * 512 + col0);
#pragma unroll
        for (int e = 0; e < 8; ++e) hs[e] += (float)v[e];
    }
    float invZ = 1.0f / Z;
    bf16x8 o;
#pragma unroll
    for (int e = 0; e < 8; ++e) {
        float v = hs[e] * invZ;
        o[e] = (bf16_t)(v > 0.f ? v : expm1f(v));
    }
    *(bf16x8*)(hcatb + (size_t)i * 512 + col0) = o;
}

// ---- combine split-K gemm2 slices: VT2 bf16 + s1o/s2o dots. block=128thr=1 row.
__global__ __launch_bounds__(128) void comb2_k(const float* __restrict__ Cp,
                                               const float* __restrict__ a1o,
                                               const float* __restrict__ a2o,
                                               bf16_t* __restrict__ VT2,
                                               float* __restrict__ s1o,
                                               float* __restrict__ s2o) {
    int r = blockIdx.x, t = threadIdx.x;
    float w = 0.f;
#pragma unroll
    for (int z = 0; z < 4; ++z) w += Cp[((size_t)z * NN + r) * 128 + t];
    VT2[(size_t)t * NN + r] = (bf16_t)w;
    float d1 = w * a1o[t], d2 = w * a2o[t];
#pragma unroll
    for (int o = 1; o < 64; o <<= 1) { d1 += __shfl_xor(d1, o); d2 += __shfl_xor(d2, o); }
    __shared__ float red[4];
    if ((t & 63) == 0) { red[(t >> 6) * 2 + 0] = d1; red[(t >> 6) * 2 + 1] = d2; }
    __syncthreads();
    if (t == 0) {
        s1o[r] = (red[0] + red[2]) * LOG2E;
        s2o[r] = (red[1] + red[3]) * LOG2E;
    }
}

// ---- finalize layer 2: out fp32 = sum H / sum Z, 8 cols/thread
__global__ __launch_bounds__(256) void fin2_k(const bf16_t* __restrict__ Hpart,
                                              const float* __restrict__ zpart,
                                              float* __restrict__ out) {
    int idx = blockIdx.x * 256 + threadIdx.x;   // < N*16
    int i = idx >> 4, col0 = (idx & 15) << 3;
    float Z = 0.f;
#pragma unroll
    for (int jz = 0; jz < 16; ++jz) Z += zpart[(size_t)jz * NN + i];
    float hs[8];
#pragma unroll
    for (int e = 0; e < 8; ++e) hs[e] = 0.f;
#pragma unroll
    for (int jz = 0; jz < 16; ++jz) {
        bf16x8 v = *(const bf16x8*)(Hpart + ((size_t)jz * NN + i) * 128 + col0);
#pragma unroll
        for (int e = 0; e < 8; ++e) hs[e] += (float)v[e];
    }
    float invZ = 1.0f / Z;
    f32x4 o0, o1;
#pragma unroll
    for (int e = 0; e < 4; ++e) { o0[e] = hs[e] * invZ; o1[e] = hs[e + 4] * invZ; }
    *(f32x4*)(out + (size_t)i * 128 + col0) = o0;
    *(f32x4*)(out + (size_t)i * 128 + col0 + 4) = o1;
}

extern "C" void kernel_launch(void* const* d_in, const int* in_sizes, int n_in,
                              void* d_out, int out_size, void* d_ws, size_t ws_size,
                              hipStream_t stream) {
    const int N = 4096;
    const float* x       = (const float*)d_in[0];
    const int*   adj     = (const int*)d_in[1];
    const float* W_heads = (const float*)d_in[2];
    const float* a1h     = (const float*)d_in[3];
    const float* a2h     = (const float*)d_in[4];
    const float* W_out   = (const float*)d_in[5];
    const float* a1o     = (const float*)d_in[6];
    const float* a2o     = (const float*)d_in[7];
    (void)in_sizes; (void)n_in; (void)out_size; (void)ws_size;

    size_t off = 0;
    auto alloc = [&](size_t bytes) { size_t o = off; off = (off + bytes + 255) & ~(size_t)255; return o; };
    char* ws = (char*)d_ws;
    uint32_t* bits  = (uint32_t*)(ws + alloc((size_t)N * N / 8));        // 2 MB
    bf16_t* VT1     = (bf16_t*)(ws + alloc((size_t)512 * N * 2));        // 4 MB
    bf16_t* hcatb   = (bf16_t*)(ws + alloc((size_t)N * 512 * 2));        // 4 MB
    bf16_t* WoutT   = (bf16_t*)(ws + alloc((size_t)128 * 512 * 2));      // 128 KB
    float*  s1h     = (float*)(ws + alloc((size_t)8 * N * 4));
    float*  s2h     = (float*)(ws + alloc((size_t)8 * N * 4));
    float*  s1o     = (float*)(ws + alloc((size_t)N * 4));
    float*  s2o     = (float*)(ws + alloc((size_t)N * 4));
    bf16_t* VT2     = (bf16_t*)(ws + alloc((size_t)128 * N * 2));        // 1 MB
    float*  zpart   = (float*)(ws + alloc((size_t)64 * N * 4));          // 1 MB
    bf16_t* Hpart   = (bf16_t*)(ws + alloc((size_t)32 * 1024 * 1024));   // 32 MB
    // aliases into the Hpart region (temporally disjoint):
    bf16_t* xb    = (bf16_t*)Hpart;                       // dead after gemm1
    bf16_t* WT1   = (bf16_t*)((char*)Hpart + (4 << 20));  // dead after gemm1
    float*  Cpart = (float*)Hpart;                        // gemm2..comb2 only

    // 1. adjacency bitmask
    hipLaunchKernelGGL(pack_bits_k, dim3(2048), dim3(256), 0, stream, adj, bits, N * N);
    // 2. prep conversions/transposes
    hipLaunchKernelGGL(prep_k, dim3(1024), dim3(256), 0, stream, x, W_heads, W_out, xb, WT1, WoutT);
    // 3. gemm1: VT1 + s1h/s2h (per-head epilogue)
    hipLaunchKernelGGL((gemm_k<1, 0>), dim3(256, 8, 1), dim3(64), 0, stream,
                       xb, WT1, VT1, (float*)nullptr, a1h, a2h, s1h, s2h, 512, 512, 512);
    // 4. layer-1 aggregate: (rowtiles=128, heads=8, jz=8)
    hipLaunchKernelGGL(gat_agg_k, dim3(128, 8, 8), dim3(64), 0, stream,
                       s1h, s2h, N, bits, VT1, Hpart, zpart, 512, 512, 8);
    // 5. finalize 1 -> hcatb
    hipLaunchKernelGGL(fin1_k, dim3(1024), dim3(256), 0, stream, Hpart, zpart, hcatb);
    // 6. gemm2 split-K=4 -> Cpart
    hipLaunchKernelGGL((gemm_k<0, 1>), dim3(256, 2, 4), dim3(64), 0, stream,
                       hcatb, WoutT, (bf16_t*)nullptr, Cpart,
                       (const float*)nullptr, (const float*)nullptr,
                       (float*)nullptr, (float*)nullptr, 512, 128, 128);
    // 7. combine -> VT2, s1o, s2o
    hipLaunchKernelGGL(comb2_k, dim3(4096), dim3(128), 0, stream, Cpart, a1o, a2o, VT2, s1o, s2o);
    // 8. layer-2 aggregate: (rowtiles=128, colgrps=2, jz=16)
    hipLaunchKernelGGL(gat_agg_k, dim3(128, 2, 16), dim3(64), 0, stream,
                       s1o, s2o, 0, bits, VT2, Hpart, zpart, 128, 256, 1);
    // 9. finalize 2 -> out
    hipLaunchKernelGGL(fin2_k, dim3(256), dim3(256), 0, stream, Hpart, zpart, (float*)d_out);
}

// Round 3
// 192.655 us; speedup vs baseline: 1.0879x; 1.0879x over previous
//
#include <hip/hip_runtime.h>
#include <hip/hip_bf16.h>
#include <cstdint>

// ---------------------------------------------------------------------------
// GAT forward, N=4096, F=512, D=64, H=8, O=128, fp32 in/out.
// Key identity: exp(lrelu(u)) = max(exp(u), exp(0.2u))  [lrelu(u)=max(u,0.2u),
// exp2 monotone], and u = s1_i + s2_j is rank-1, so with row-scale invariance
// of softmax:  p'_ij = max(E2_j, g_i * F2_j),  g_i = exp(-0.8 s1_i),
// E2 = exp(s2), F2 = exp(0.2 s2).  -> NO exp / NO add in the N^2 inner loop.
//   adj -> bitmask (2MB, L2-resident)
//   gemm1 (bf16 MFMA): writes VT1=(x@Wcat)^T bf16 AND g/E2/F2 per head
//   agg:  P generated in-register (mul+max+mask+cvt), A=P bf16, B=Wh^T,
//         mfma 16x16x32; RT=4 row-tiles/wave (64 rows), jz-split grid.
//   fin1: ELU(H/Z) -> hcat bf16 ; gemm2 split-K + comb2 (VT2, g/E2/F2 out)
//   agg2, fin2 -> out.
// ---------------------------------------------------------------------------

using bf16_t = __bf16;
using bf16x4 = __attribute__((ext_vector_type(4))) __bf16;
using bf16x8 = __attribute__((ext_vector_type(8))) __bf16;
using f32x4  = __attribute__((ext_vector_type(4))) float;

#define LOG2E 1.44269504f
constexpr int NN = 4096;

// ---- pack adjacency into bitmask: bit j of word [i][j/32] = (adj[i][j] > 0)
__global__ __launch_bounds__(256) void pack_bits_k(const int* __restrict__ adj,
                                                   uint32_t* __restrict__ bits, int total) {
    int stride = gridDim.x * blockDim.x;
    for (int idx = blockIdx.x * blockDim.x + threadIdx.x; idx < total; idx += stride) {
        unsigned long long m = __ballot(adj[idx] > 0);
        int l = threadIdx.x & 63;
        if (l == 0)        bits[idx >> 5] = (uint32_t)m;
        else if (l == 32)  bits[idx >> 5] = (uint32_t)(m >> 32);
    }
}

// ---- prep: x->bf16, W_heads [H][F][D] -> WT1[(h*64+d)][F], W_out -> WoutT[o][512]
__global__ __launch_bounds__(256) void prep_k(const float* __restrict__ x,
                                              const float* __restrict__ Wh,
                                              const float* __restrict__ Wo,
                                              bf16_t* __restrict__ xb,
                                              bf16_t* __restrict__ WT1,
                                              bf16_t* __restrict__ WoutT) {
    const int NX = NN * 512, NW1 = 512 * 512, NW2 = 128 * 512;
    int stride = gridDim.x * blockDim.x;
    for (int t = blockIdx.x * blockDim.x + threadIdx.x; t < NX + NW1 + NW2; t += stride) {
        if (t < NX) {
            xb[t] = (bf16_t)x[t];
        } else if (t < NX + NW1) {
            int u = t - NX; int hd = u >> 9, f = u & 511; int h = hd >> 6, d = hd & 63;
            WT1[u] = (bf16_t)Wh[(h << 15) + (f << 6) + d];
        } else {
            int u = t - NX - NW1; int o = u >> 9, cc = u & 511;
            WoutT[u] = (bf16_t)Wo[cc * 128 + o];
        }
    }
}

// ---- bf16 MFMA GEMM, wave = 16 rows x 64 cols.
// CS: epilogue writes VT (bf16 transposed) + g/E2/F2 factors (cb = head*64)
// WC: writes fp32 partial C slice (split-K via blockIdx.z)
template<int CS, int WC>
__global__ __launch_bounds__(64) void gemm_k(const bf16_t* __restrict__ A,
                                             const bf16_t* __restrict__ BT,
                                             bf16_t* __restrict__ VTo,
                                             float* __restrict__ Cp,
                                             const float* __restrict__ a1,
                                             const float* __restrict__ a2,
                                             float* __restrict__ g1,
                                             float* __restrict__ E2,
                                             float* __restrict__ F2,
                                             int K, int NC, int kslice) {
    const int lane = threadIdx.x, lr = lane & 15, kg = lane >> 4;
    const int rowb = blockIdx.x * 16, cb = blockIdx.y * 64, kz = blockIdx.z;
    f32x4 acc[4];
#pragma unroll
    for (int dt = 0; dt < 4; ++dt) acc[dt] = 0.0f;
    const bf16_t* Ap = A + (size_t)(rowb + lr) * K;
    const int k0beg = kz * kslice, k0end = k0beg + kslice;
    for (int k0 = k0beg; k0 < k0end; k0 += 32) {
        bf16x8 af = *(const bf16x8*)(Ap + k0 + kg * 8);
#pragma unroll
        for (int dt = 0; dt < 4; ++dt) {
            bf16x8 bfr = *(const bf16x8*)(BT + (size_t)(cb + dt * 16 + lr) * K + k0 + kg * 8);
            acc[dt] = __builtin_amdgcn_mfma_f32_16x16x32_bf16(af, bfr, acc[dt], 0, 0, 0);
        }
    }
    if (WC) {
#pragma unroll
        for (int dt = 0; dt < 4; ++dt)
#pragma unroll
            for (int r = 0; r < 4; ++r)
                Cp[((size_t)kz * NN + rowb + kg * 4 + r) * NC + cb + dt * 16 + lr] = acc[dt][r];
    }
    if (CS) {
#pragma unroll
        for (int dt = 0; dt < 4; ++dt) {
            bf16x4 v;
#pragma unroll
            for (int r = 0; r < 4; ++r) v[r] = (bf16_t)acc[dt][r];
            *(bf16x4*)(VTo + (size_t)(cb + dt * 16 + lr) * NN + rowb + kg * 4) = v;
        }
        float a1v[4], a2v[4];
#pragma unroll
        for (int dt = 0; dt < 4; ++dt) {
            a1v[dt] = a1[cb + dt * 16 + lr];
            a2v[dt] = a2[cb + dt * 16 + lr];
        }
#pragma unroll
        for (int r = 0; r < 4; ++r) {
            float d1 = 0.f, d2 = 0.f;
#pragma unroll
            for (int dt = 0; dt < 4; ++dt) { d1 += acc[dt][r] * a1v[dt]; d2 += acc[dt][r] * a2v[dt]; }
#pragma unroll
            for (int o = 1; o < 16; o <<= 1) { d1 += __shfl_xor(d1, o); d2 += __shfl_xor(d2, o); }
            if (lr == 0) {
                size_t row = (size_t)blockIdx.y * NN + rowb + kg * 4 + r;
                g1[row] = exp2f(-0.8f * LOG2E * d1);
                E2[row] = exp2f(LOG2E * d2);
                F2[row] = exp2f(0.2f * LOG2E * d2);
            }
        }
    }
}

// ---- fused attention-aggregate: wave = 64 rows x 64 cols (colgrp c), j-range jz.
// p'_ij = adj ? max(E2_j, g_i*F2_j) : 0   (row-rescaled softmax numerator)
// Hpart[jz] (bf16) = P*V partial; zpart[zi] = row sums of P (VALU adds).
__global__ __launch_bounds__(64, 3) void gat_agg_k(const float* __restrict__ g1,
                                                   const float* __restrict__ E2,
                                                   const float* __restrict__ F2, int shead,
                                                   const uint32_t* __restrict__ bits,
                                                   const bf16_t* __restrict__ VT,
                                                   bf16_t* __restrict__ Hpart,
                                                   float* __restrict__ zpart,
                                                   int CT, int JR, int ZC) {
    const int lane = threadIdx.x, lr = lane & 15, kg = lane >> 4;
    const int rowb = blockIdx.x * 64, c = blockIdx.y, jz = blockIdx.z;
    const int cb = c * 64;
    const float* gp  = g1 + (size_t)shead * c;
    const float* E2p = E2 + (size_t)shead * c;
    const float* F2p = F2 + (size_t)shead * c;
    const int steps = JR >> 5, jb0 = jz * JR;

    f32x4 acc[4][4];
#pragma unroll
    for (int rt = 0; rt < 4; ++rt)
#pragma unroll
        for (int dt = 0; dt < 4; ++dt) acc[rt][dt] = 0.0f;
    float zacc[4] = {0.f, 0.f, 0.f, 0.f};
    float gv[4];
    const uint32_t* brow[4];
#pragma unroll
    for (int rt = 0; rt < 4; ++rt) {
        int row = rowb + rt * 16 + lr;
        gv[rt] = gp[row];
        brow[rt] = bits + (size_t)row * (NN / 32);
    }

    for (int js = 0; js < steps; ++js) {
        const int jb = jb0 + js * 32, jk = jb + kg * 8;
        f32x4 e2a = *(const f32x4*)(E2p + jk);
        f32x4 e2b = *(const f32x4*)(E2p + jk + 4);
        f32x4 f2a = *(const f32x4*)(F2p + jk);
        f32x4 f2b = *(const f32x4*)(F2p + jk + 4);
        bf16x8 bfr[4];
#pragma unroll
        for (int dt = 0; dt < 4; ++dt)
            bfr[dt] = *(const bf16x8*)(VT + (size_t)(cb + dt * 16 + lr) * NN + jk);
#pragma unroll
        for (int rt = 0; rt < 4; ++rt) {
            uint32_t mb = (brow[rt][jb >> 5] >> (kg * 8)) & 0xffu;
            bf16x8 af;
            float zs = 0.f;
#pragma unroll
            for (int e = 0; e < 8; ++e) {
                float e2 = (e < 4) ? e2a[e] : e2b[e - 4];
                float f2 = (e < 4) ? f2a[e] : f2b[e - 4];
                float p = fmaxf(e2, gv[rt] * f2);
                p = (mb & (1u << e)) ? p : 0.0f;
                zs += p;
                af[e] = (bf16_t)p;
            }
            zacc[rt] += zs;
#pragma unroll
            for (int dt = 0; dt < 4; ++dt)
                acc[rt][dt] = __builtin_amdgcn_mfma_f32_16x16x32_bf16(af, bfr[dt], acc[rt][dt], 0, 0, 0);
        }
    }

    bf16_t* Hp = Hpart + (size_t)jz * NN * CT;
#pragma unroll
    for (int rt = 0; rt < 4; ++rt) {
        float z = zacc[rt];
        z += __shfl_xor(z, 16);
        z += __shfl_xor(z, 32);
        if (lane < 16 && (ZC > 1 || c == 0)) {
            int zi = jz * ZC + (ZC > 1 ? c : 0);
            zpart[(size_t)zi * NN + rowb + rt * 16 + lr] = z;
        }
#pragma unroll
        for (int dt = 0; dt < 4; ++dt)
#pragma unroll
            for (int r = 0; r < 4; ++r)
                Hp[(size_t)(rowb + rt * 16 + kg * 4 + r) * CT + cb + dt * 16 + lr] = (bf16_t)acc[rt][dt][r];
    }
}

// ---- finalize layer 1: hcatb = bf16(ELU(sum H / sum Z)), 8 cols/thread
__global__ __launch_bounds__(256) void fin1_k(const bf16_t* __restrict__ Hpart,
                                              const float* __restrict__ zpart,
                                              bf16_t* __restrict__ hcatb) {
    int idx = blockIdx.x * 256 + threadIdx.x;   // < N*64
    int i = idx >> 6, col0 = (idx & 63) << 3, h = col0 >> 6;
    float Z = 0.f;
#pragma unroll
    for (int jz = 0; jz < 8; ++jz) Z += zpart[(size_t)(jz * 8 + h) * NN + i];
    float hs[8];
#pragma unroll
    for (int e = 0; e < 8; ++e) hs[e] = 0.f;
#pragma unroll
    for (int jz = 0; jz < 8; ++jz) {
        bf16x8 v = *(const bf16x8*)(Hpart + ((size_t)jz * NN + i) * 512 + col0);
#pragma unroll
        for (int e = 0; e < 8; ++e) hs[e] += (float)v[e];
    }
    float invZ = 1.0f / Z;
    bf16x8 o;
#pragma unroll
    for (int e = 0; e < 8; ++e) {
        float v = hs[e] * invZ;
        o[e] = (bf16_t)(v > 0.f ? v : expm1f(v));
    }
    *(bf16x8*)(hcatb + (size_t)i * 512 + col0) = o;
}

// ---- combine split-K gemm2 slices: VT2 bf16 + g/E2/F2 factors. block=128thr=1 row.
__global__ __launch_bounds__(128) void comb2_k(const float* __restrict__ Cp,
                                               const float* __restrict__ a1o,
                                               const float* __restrict__ a2o,
                                               bf16_t* __restrict__ VT2,
                                               float* __restrict__ g1o,
                                               float* __restrict__ E2o,
                                               float* __restrict__ F2o) {
    int r = blockIdx.x, t = threadIdx.x;
    float w = 0.f;
#pragma unroll
    for (int z = 0; z < 4; ++z) w += Cp[((size_t)z * NN + r) * 128 + t];
    VT2[(size_t)t * NN + r] = (bf16_t)w;
    float d1 = w * a1o[t], d2 = w * a2o[t];
#pragma unroll
    for (int o = 1; o < 64; o <<= 1) { d1 += __shfl_xor(d1, o); d2 += __shfl_xor(d2, o); }
    __shared__ float red[4];
    if ((t & 63) == 0) { red[(t >> 6) * 2 + 0] = d1; red[(t >> 6) * 2 + 1] = d2; }
    __syncthreads();
    if (t == 0) {
        float s1 = red[0] + red[2], s2 = red[1] + red[3];
        g1o[r] = exp2f(-0.8f * LOG2E * s1);
        E2o[r] = exp2f(LOG2E * s2);
        F2o[r] = exp2f(0.2f * LOG2E * s2);
    }
}

// ---- finalize layer 2: out fp32 = sum H / sum Z, 8 cols/thread
__global__ __launch_bounds__(256) void fin2_k(const bf16_t* __restrict__ Hpart,
                                              const float* __restrict__ zpart,
                                              float* __restrict__ out) {
    int idx = blockIdx.x * 256 + threadIdx.x;   // < N*16
    int i = idx >> 4, col0 = (idx & 15) << 3;
    float Z = 0.f;
#pragma unroll
    for (int jz = 0; jz < 16; ++jz) Z += zpart[(size_t)jz * NN + i];
    float hs[8];
#pragma unroll
    for (int e = 0; e < 8; ++e) hs[e] = 0.f;
#pragma unroll
    for (int jz = 0; jz < 16; ++jz) {
        bf16x8 v = *(const bf16x8*)(Hpart + ((size_t)jz * NN + i) * 128 + col0);
#pragma unroll
        for (int e = 0; e < 8; ++e) hs[e] += (float)v[e];
    }
    float invZ = 1.0f / Z;
    f32x4 o0, o1;
#pragma unroll
    for (int e = 0; e < 4; ++e) { o0[e] = hs[e] * invZ; o1[e] = hs[e + 4] * invZ; }
    *(f32x4*)(out + (size_t)i * 128 + col0) = o0;
    *(f32x4*)(out + (size_t)i * 128 + col0 + 4) = o1;
}

extern "C" void kernel_launch(void* const* d_in, const int* in_sizes, int n_in,
                              void* d_out, int out_size, void* d_ws, size_t ws_size,
                              hipStream_t stream) {
    const int N = 4096;
    const float* x       = (const float*)d_in[0];
    const int*   adj     = (const int*)d_in[1];
    const float* W_heads = (const float*)d_in[2];
    const float* a1h     = (const float*)d_in[3];
    const float* a2h     = (const float*)d_in[4];
    const float* W_out   = (const float*)d_in[5];
    const float* a1o     = (const float*)d_in[6];
    const float* a2o     = (const float*)d_in[7];
    (void)in_sizes; (void)n_in; (void)out_size; (void)ws_size;

    size_t off = 0;
    auto alloc = [&](size_t bytes) { size_t o = off; off = (off + bytes + 255) & ~(size_t)255; return o; };
    char* ws = (char*)d_ws;
    uint32_t* bits  = (uint32_t*)(ws + alloc((size_t)N * N / 8));        // 2 MB
    bf16_t* VT1     = (bf16_t*)(ws + alloc((size_t)512 * N * 2));        // 4 MB
    bf16_t* hcatb   = (bf16_t*)(ws + alloc((size_t)N * 512 * 2));        // 4 MB
    bf16_t* WoutT   = (bf16_t*)(ws + alloc((size_t)128 * 512 * 2));      // 128 KB
    float*  g1h     = (float*)(ws + alloc((size_t)8 * N * 4));
    float*  E2h     = (float*)(ws + alloc((size_t)8 * N * 4));
    float*  F2h     = (float*)(ws + alloc((size_t)8 * N * 4));
    float*  g1o     = (float*)(ws + alloc((size_t)N * 4));
    float*  E2o     = (float*)(ws + alloc((size_t)N * 4));
    float*  F2o     = (float*)(ws + alloc((size_t)N * 4));
    bf16_t* VT2     = (bf16_t*)(ws + alloc((size_t)128 * N * 2));        // 1 MB
    float*  zpart   = (float*)(ws + alloc((size_t)64 * N * 4));          // 1 MB
    bf16_t* Hpart   = (bf16_t*)(ws + alloc((size_t)32 * 1024 * 1024));   // 32 MB
    // aliases into the Hpart region (temporally disjoint):
    bf16_t* xb    = (bf16_t*)Hpart;                       // dead after gemm1
    bf16_t* WT1   = (bf16_t*)((char*)Hpart + (4 << 20));  // dead after gemm1
    float*  Cpart = (float*)Hpart;                        // gemm2..comb2 only

    // 1. adjacency bitmask
    hipLaunchKernelGGL(pack_bits_k, dim3(2048), dim3(256), 0, stream, adj, bits, N * N);
    // 2. prep conversions/transposes
    hipLaunchKernelGGL(prep_k, dim3(1024), dim3(256), 0, stream, x, W_heads, W_out, xb, WT1, WoutT);
    // 3. gemm1: VT1 + g/E2/F2 per head
    hipLaunchKernelGGL((gemm_k<1, 0>), dim3(256, 8, 1), dim3(64), 0, stream,
                       xb, WT1, VT1, (float*)nullptr, a1h, a2h, g1h, E2h, F2h, 512, 512, 512);
    // 4. layer-1 aggregate: (rowtiles=64, heads=8, jz=8)
    hipLaunchKernelGGL(gat_agg_k, dim3(64, 8, 8), dim3(64), 0, stream,
                       g1h, E2h, F2h, N, bits, VT1, Hpart, zpart, 512, 512, 8);
    // 5. finalize 1 -> hcatb
    hipLaunchKernelGGL(fin1_k, dim3(1024), dim3(256), 0, stream, Hpart, zpart, hcatb);
    // 6. gemm2 split-K=4 -> Cpart
    hipLaunchKernelGGL((gemm_k<0, 1>), dim3(256, 2, 4), dim3(64), 0, stream,
                       hcatb, WoutT, (bf16_t*)nullptr, Cpart,
                       (const float*)nullptr, (const float*)nullptr,
                       (float*)nullptr, (float*)nullptr, (float*)nullptr, 512, 128, 128);
    // 7. combine -> VT2, g1o/E2o/F2o
    hipLaunchKernelGGL(comb2_k, dim3(4096), dim3(128), 0, stream, Cpart, a1o, a2o, VT2, g1o, E2o, F2o);
    // 8. layer-2 aggregate: (rowtiles=64, colgrps=2, jz=16)
    hipLaunchKernelGGL(gat_agg_k, dim3(64, 2, 16), dim3(64), 0, stream,
                       g1o, E2o, F2o, 0, bits, VT2, Hpart, zpart, 128, 256, 1);
    // 9. finalize 2 -> out
    hipLaunchKernelGGL(fin2_k, dim3(256), dim3(256), 0, stream, Hpart, zpart, (float*)d_out);
}

// Round 4
// 173.963 us; speedup vs baseline: 1.2048x; 1.1074x over previous
//
#include <hip/hip_runtime.h>
#include <hip/hip_bf16.h>
#include <cstdint>

// ---------------------------------------------------------------------------
// GAT forward, N=4096, F=512, D=64, H=8, O=128, fp32 in/out.
// Identity: exp(lrelu(u)) = max(exp(u), exp(0.2u)); u = s1_i+s2_j rank-1;
// softmax row-scale invariance => p'_ij = max(E2_j, g_i*F2_j), g=exp(-0.8 s1).
// agg kernels: 4-wave workgroups (wave = jz slice), register double-buffered
// loads (A/B named sets) so VT/bits/E2/F2 for step s+1 are in flight during
// compute of step s  -> latency-bound fix for round 3's 28% VALUBusy.
// ---------------------------------------------------------------------------

using bf16_t = __bf16;
using bf16x4 = __attribute__((ext_vector_type(4))) __bf16;
using bf16x8 = __attribute__((ext_vector_type(8))) __bf16;
using f32x4  = __attribute__((ext_vector_type(4))) float;

#define LOG2E 1.44269504f
constexpr int NN = 4096;

// ---- pack adjacency into bitmask: bit j of word [i][j/32] = (adj[i][j] > 0)
__global__ __launch_bounds__(256) void pack_bits_k(const int* __restrict__ adj,
                                                   uint32_t* __restrict__ bits, int total) {
    int stride = gridDim.x * blockDim.x;
    for (int idx = blockIdx.x * blockDim.x + threadIdx.x; idx < total; idx += stride) {
        unsigned long long m = __ballot(adj[idx] > 0);
        int l = threadIdx.x & 63;
        if (l == 0)        bits[idx >> 5] = (uint32_t)m;
        else if (l == 32)  bits[idx >> 5] = (uint32_t)(m >> 32);
    }
}

// ---- prep: x->bf16, W_heads [H][F][D] -> WT1[(h*64+d)][F], W_out -> WoutT[o][512]
__global__ __launch_bounds__(256) void prep_k(const float* __restrict__ x,
                                              const float* __restrict__ Wh,
                                              const float* __restrict__ Wo,
                                              bf16_t* __restrict__ xb,
                                              bf16_t* __restrict__ WT1,
                                              bf16_t* __restrict__ WoutT) {
    const int NX = NN * 512, NW1 = 512 * 512, NW2 = 128 * 512;
    int stride = gridDim.x * blockDim.x;
    for (int t = blockIdx.x * blockDim.x + threadIdx.x; t < NX + NW1 + NW2; t += stride) {
        if (t < NX) {
            xb[t] = (bf16_t)x[t];
        } else if (t < NX + NW1) {
            int u = t - NX; int hd = u >> 9, f = u & 511; int h = hd >> 6, d = hd & 63;
            WT1[u] = (bf16_t)Wh[(h << 15) + (f << 6) + d];
        } else {
            int u = t - NX - NW1; int o = u >> 9, cc = u & 511;
            WoutT[u] = (bf16_t)Wo[cc * 128 + o];
        }
    }
}

// ---- bf16 MFMA GEMM, 4 waves/block, wave = 16 rows x 64 cols.
// CS: epilogue writes VT (bf16 transposed) + g/E2/F2 factors (cb = head*64)
// WC: writes fp32 partial C slice (split-K via blockIdx.z)
template<int CS, int WC>
__global__ __launch_bounds__(256) void gemm_k(const bf16_t* __restrict__ A,
                                              const bf16_t* __restrict__ BT,
                                              bf16_t* __restrict__ VTo,
                                              float* __restrict__ Cp,
                                              const float* __restrict__ a1,
                                              const float* __restrict__ a2,
                                              float* __restrict__ g1,
                                              float* __restrict__ E2,
                                              float* __restrict__ F2,
                                              int K, int NC, int kslice) {
    const int wave = threadIdx.x >> 6, lane = threadIdx.x & 63;
    const int lr = lane & 15, kg = lane >> 4;
    const int rowb = (blockIdx.x * 4 + wave) * 16, cb = blockIdx.y * 64, kz = blockIdx.z;
    f32x4 acc[4];
#pragma unroll
    for (int dt = 0; dt < 4; ++dt) acc[dt] = 0.0f;
    const bf16_t* Ap = A + (size_t)(rowb + lr) * K;
    const int k0beg = kz * kslice, k0end = k0beg + kslice;
    for (int k0 = k0beg; k0 < k0end; k0 += 32) {
        bf16x8 af = *(const bf16x8*)(Ap + k0 + kg * 8);
#pragma unroll
        for (int dt = 0; dt < 4; ++dt) {
            bf16x8 bfr = *(const bf16x8*)(BT + (size_t)(cb + dt * 16 + lr) * K + k0 + kg * 8);
            acc[dt] = __builtin_amdgcn_mfma_f32_16x16x32_bf16(af, bfr, acc[dt], 0, 0, 0);
        }
    }
    if (WC) {
#pragma unroll
        for (int dt = 0; dt < 4; ++dt)
#pragma unroll
            for (int r = 0; r < 4; ++r)
                Cp[((size_t)kz * NN + rowb + kg * 4 + r) * NC + cb + dt * 16 + lr] = acc[dt][r];
    }
    if (CS) {
#pragma unroll
        for (int dt = 0; dt < 4; ++dt) {
            bf16x4 v;
#pragma unroll
            for (int r = 0; r < 4; ++r) v[r] = (bf16_t)acc[dt][r];
            *(bf16x4*)(VTo + (size_t)(cb + dt * 16 + lr) * NN + rowb + kg * 4) = v;
        }
        float a1v[4], a2v[4];
#pragma unroll
        for (int dt = 0; dt < 4; ++dt) {
            a1v[dt] = a1[cb + dt * 16 + lr];
            a2v[dt] = a2[cb + dt * 16 + lr];
        }
#pragma unroll
        for (int r = 0; r < 4; ++r) {
            float d1 = 0.f, d2 = 0.f;
#pragma unroll
            for (int dt = 0; dt < 4; ++dt) { d1 += acc[dt][r] * a1v[dt]; d2 += acc[dt][r] * a2v[dt]; }
#pragma unroll
            for (int o = 1; o < 16; o <<= 1) { d1 += __shfl_xor(d1, o); d2 += __shfl_xor(d2, o); }
            if (lr == 0) {
                size_t row = (size_t)blockIdx.y * NN + rowb + kg * 4 + r;
                g1[row] = exp2f(-0.8f * LOG2E * d1);
                E2[row] = exp2f(LOG2E * d2);
                F2[row] = exp2f(0.2f * LOG2E * d2);
            }
        }
    }
}

// ---- fused attention-aggregate: 4 waves/block; wave w owns jz = bz*4+w.
// wave = 64 rows x 64 cols (colgrp c). p'_ij = adj ? max(E2_j, g_i*F2_j) : 0.
// Register double-buffer: step s+1's VT frags / E2/F2 / bits in flight
// during compute of step s.
__global__ __launch_bounds__(256) void gat_agg_k(const float* __restrict__ g1,
                                                 const float* __restrict__ E2,
                                                 const float* __restrict__ F2, int shead,
                                                 const uint32_t* __restrict__ bits,
                                                 const bf16_t* __restrict__ VT,
                                                 bf16_t* __restrict__ Hpart,
                                                 float* __restrict__ zpart,
                                                 int CT, int JR, int ZC) {
    const int wave = threadIdx.x >> 6, lane = threadIdx.x & 63;
    const int lr = lane & 15, kg = lane >> 4;
    const int rowb = blockIdx.x * 64, c = blockIdx.y;
    const int jz = blockIdx.z * 4 + wave;
    const int cb = c * 64;
    const float* gp  = g1 + (size_t)shead * c;
    const float* E2p = E2 + (size_t)shead * c;
    const float* F2p = F2 + (size_t)shead * c;
    const int steps = JR >> 5, jb0 = jz * JR;

    f32x4 acc[4][4];
#pragma unroll
    for (int rt = 0; rt < 4; ++rt)
#pragma unroll
        for (int dt = 0; dt < 4; ++dt) acc[rt][dt] = 0.0f;
    float zacc[4] = {0.f, 0.f, 0.f, 0.f};
    float gv[4];
    const uint32_t* brow[4];
#pragma unroll
    for (int rt = 0; rt < 4; ++rt) {
        int row = rowb + rt * 16 + lr;
        gv[rt] = gp[row];
        brow[rt] = bits + (size_t)row * (NN / 32);
    }

    auto LOAD = [&](int jb, bf16x8* bfr, f32x4& e2a, f32x4& e2b, f32x4& f2a, f32x4& f2b,
                    uint32_t* bw) {
        const int jk = jb + kg * 8;
        e2a = *(const f32x4*)(E2p + jk);
        e2b = *(const f32x4*)(E2p + jk + 4);
        f2a = *(const f32x4*)(F2p + jk);
        f2b = *(const f32x4*)(F2p + jk + 4);
#pragma unroll
        for (int dt = 0; dt < 4; ++dt)
            bfr[dt] = *(const bf16x8*)(VT + (size_t)(cb + dt * 16 + lr) * NN + jk);
#pragma unroll
        for (int rt = 0; rt < 4; ++rt)
            bw[rt] = brow[rt][jb >> 5];
    };
    auto COMP = [&](const bf16x8* bfr, f32x4 e2a, f32x4 e2b, f32x4 f2a, f32x4 f2b,
                    const uint32_t* bw) {
#pragma unroll
        for (int rt = 0; rt < 4; ++rt) {
            uint32_t mb = (bw[rt] >> (kg * 8)) & 0xffu;
            bf16x8 af;
            float zs = 0.f;
#pragma unroll
            for (int e = 0; e < 8; ++e) {
                float e2 = (e < 4) ? e2a[e] : e2b[e - 4];
                float f2 = (e < 4) ? f2a[e] : f2b[e - 4];
                float p = fmaxf(e2, gv[rt] * f2);
                p = (mb & (1u << e)) ? p : 0.0f;
                zs += p;
                af[e] = (bf16_t)p;
            }
            zacc[rt] += zs;
#pragma unroll
            for (int dt = 0; dt < 4; ++dt)
                acc[rt][dt] = __builtin_amdgcn_mfma_f32_16x16x32_bf16(af, bfr[dt], acc[rt][dt], 0, 0, 0);
        }
    };

    bf16x8 bA[4], bB[4];
    f32x4 eaA, ebA, faA, fbA, eaB, ebB, faB, fbB;
    uint32_t wA[4], wB[4];
    LOAD(jb0, bA, eaA, ebA, faA, fbA, wA);
    for (int js = 0; js < steps - 2; js += 2) {
        LOAD(jb0 + (js + 1) * 32, bB, eaB, ebB, faB, fbB, wB);
        COMP(bA, eaA, ebA, faA, fbA, wA);
        LOAD(jb0 + (js + 2) * 32, bA, eaA, ebA, faA, fbA, wA);
        COMP(bB, eaB, ebB, faB, fbB, wB);
    }
    LOAD(jb0 + (steps - 1) * 32, bB, eaB, ebB, faB, fbB, wB);
    COMP(bA, eaA, ebA, faA, fbA, wA);
    COMP(bB, eaB, ebB, faB, fbB, wB);

    bf16_t* Hp = Hpart + (size_t)jz * NN * CT;
#pragma unroll
    for (int rt = 0; rt < 4; ++rt) {
        float z = zacc[rt];
        z += __shfl_xor(z, 16);
        z += __shfl_xor(z, 32);
        if (lane < 16 && (ZC > 1 || c == 0)) {
            int zi = jz * ZC + (ZC > 1 ? c : 0);
            zpart[(size_t)zi * NN + rowb + rt * 16 + lr] = z;
        }
#pragma unroll
        for (int dt = 0; dt < 4; ++dt)
#pragma unroll
            for (int r = 0; r < 4; ++r)
                Hp[(size_t)(rowb + rt * 16 + kg * 4 + r) * CT + cb + dt * 16 + lr] = (bf16_t)acc[rt][dt][r];
    }
}

// ---- finalize layer 1: hcatb = bf16(ELU(sum H / sum Z)), 8 cols/thread
__global__ __launch_bounds__(256) void fin1_k(const bf16_t* __restrict__ Hpart,
                                              const float* __restrict__ zpart,
                                              bf16_t* __restrict__ hcatb) {
    int idx = blockIdx.x * 256 + threadIdx.x;   // < N*64
    int i = idx >> 6, col0 = (idx & 63) << 3, h = col0 >> 6;
    float Z = 0.f;
#pragma unroll
    for (int jz = 0; jz < 8; ++jz) Z += zpart[(size_t)(jz * 8 + h) * NN + i];
    float hs[8];
#pragma unroll
    for (int e = 0; e < 8; ++e) hs[e] = 0.f;
#pragma unroll
    for (int jz = 0; jz < 8; ++jz) {
        bf16x8 v = *(const bf16x8*)(Hpart + ((size_t)jz * NN + i) * 512 + col0);
#pragma unroll
        for (int e = 0; e < 8; ++e) hs[e] += (float)v[e];
    }
    float invZ = 1.0f / Z;
    bf16x8 o;
#pragma unroll
    for (int e = 0; e < 8; ++e) {
        float v = hs[e] * invZ;
        o[e] = (bf16_t)(v > 0.f ? v : expm1f(v));
    }
    *(bf16x8*)(hcatb + (size_t)i * 512 + col0) = o;
}

// ---- combine split-K gemm2 slices: VT2 bf16 + g/E2/F2 factors. block=128thr=1 row.
__global__ __launch_bounds__(128) void comb2_k(const float* __restrict__ Cp,
                                               const float* __restrict__ a1o,
                                               const float* __restrict__ a2o,
                                               bf16_t* __restrict__ VT2,
                                               float* __restrict__ g1o,
                                               float* __restrict__ E2o,
                                               float* __restrict__ F2o) {
    int r = blockIdx.x, t = threadIdx.x;
    float w = 0.f;
#pragma unroll
    for (int z = 0; z < 4; ++z) w += Cp[((size_t)z * NN + r) * 128 + t];
    VT2[(size_t)t * NN + r] = (bf16_t)w;
    float d1 = w * a1o[t], d2 = w * a2o[t];
#pragma unroll
    for (int o = 1; o < 64; o <<= 1) { d1 += __shfl_xor(d1, o); d2 += __shfl_xor(d2, o); }
    __shared__ float red[4];
    if ((t & 63) == 0) { red[(t >> 6) * 2 + 0] = d1; red[(t >> 6) * 2 + 1] = d2; }
    __syncthreads();
    if (t == 0) {
        float s1 = red[0] + red[2], s2 = red[1] + red[3];
        g1o[r] = exp2f(-0.8f * LOG2E * s1);
        E2o[r] = exp2f(LOG2E * s2);
        F2o[r] = exp2f(0.2f * LOG2E * s2);
    }
}

// ---- finalize layer 2: out fp32 = sum H / sum Z, 8 cols/thread
__global__ __launch_bounds__(256) void fin2_k(const bf16_t* __restrict__ Hpart,
                                              const float* __restrict__ zpart,
                                              float* __restrict__ out) {
    int idx = blockIdx.x * 256 + threadIdx.x;   // < N*16
    int i = idx >> 4, col0 = (idx & 15) << 3;
    float Z = 0.f;
#pragma unroll
    for (int jz = 0; jz < 16; ++jz) Z += zpart[(size_t)jz * NN + i];
    float hs[8];
#pragma unroll
    for (int e = 0; e < 8; ++e) hs[e] = 0.f;
#pragma unroll
    for (int jz = 0; jz < 16; ++jz) {
        bf16x8 v = *(const bf16x8*)(Hpart + ((size_t)jz * NN + i) * 128 + col0);
#pragma unroll
        for (int e = 0; e < 8; ++e) hs[e] += (float)v[e];
    }
    float invZ = 1.0f / Z;
    f32x4 o0, o1;
#pragma unroll
    for (int e = 0; e < 4; ++e) { o0[e] = hs[e] * invZ; o1[e] = hs[e + 4] * invZ; }
    *(f32x4*)(out + (size_t)i * 128 + col0) = o0;
    *(f32x4*)(out + (size_t)i * 128 + col0 + 4) = o1;
}

extern "C" void kernel_launch(void* const* d_in, const int* in_sizes, int n_in,
                              void* d_out, int out_size, void* d_ws, size_t ws_size,
                              hipStream_t stream) {
    const int N = 4096;
    const float* x       = (const float*)d_in[0];
    const int*   adj     = (const int*)d_in[1];
    const float* W_heads = (const float*)d_in[2];
    const float* a1h     = (const float*)d_in[3];
    const float* a2h     = (const float*)d_in[4];
    const float* W_out   = (const float*)d_in[5];
    const float* a1o     = (const float*)d_in[6];
    const float* a2o     = (const float*)d_in[7];
    (void)in_sizes; (void)n_in; (void)out_size; (void)ws_size;

    size_t off = 0;
    auto alloc = [&](size_t bytes) { size_t o = off; off = (off + bytes + 255) & ~(size_t)255; return o; };
    char* ws = (char*)d_ws;
    uint32_t* bits  = (uint32_t*)(ws + alloc((size_t)N * N / 8));        // 2 MB
    bf16_t* VT1     = (bf16_t*)(ws + alloc((size_t)512 * N * 2));        // 4 MB
    bf16_t* hcatb   = (bf16_t*)(ws + alloc((size_t)N * 512 * 2));        // 4 MB
    bf16_t* WoutT   = (bf16_t*)(ws + alloc((size_t)128 * 512 * 2));      // 128 KB
    float*  g1h     = (float*)(ws + alloc((size_t)8 * N * 4));
    float*  E2h     = (float*)(ws + alloc((size_t)8 * N * 4));
    float*  F2h     = (float*)(ws + alloc((size_t)8 * N * 4));
    float*  g1o     = (float*)(ws + alloc((size_t)N * 4));
    float*  E2o     = (float*)(ws + alloc((size_t)N * 4));
    float*  F2o     = (float*)(ws + alloc((size_t)N * 4));
    bf16_t* VT2     = (bf16_t*)(ws + alloc((size_t)128 * N * 2));        // 1 MB
    float*  zpart   = (float*)(ws + alloc((size_t)64 * N * 4));          // 1 MB
    bf16_t* Hpart   = (bf16_t*)(ws + alloc((size_t)32 * 1024 * 1024));   // 32 MB
    // aliases into the Hpart region (temporally disjoint):
    bf16_t* xb    = (bf16_t*)Hpart;                       // dead after gemm1
    bf16_t* WT1   = (bf16_t*)((char*)Hpart + (4 << 20));  // dead after gemm1
    float*  Cpart = (float*)Hpart;                        // gemm2..comb2 only

    // 1. adjacency bitmask
    hipLaunchKernelGGL(pack_bits_k, dim3(2048), dim3(256), 0, stream, adj, bits, N * N);
    // 2. prep conversions/transposes
    hipLaunchKernelGGL(prep_k, dim3(1024), dim3(256), 0, stream, x, W_heads, W_out, xb, WT1, WoutT);
    // 3. gemm1: VT1 + g/E2/F2 per head  (4-wave blocks)
    hipLaunchKernelGGL((gemm_k<1, 0>), dim3(64, 8, 1), dim3(256), 0, stream,
                       xb, WT1, VT1, (float*)nullptr, a1h, a2h, g1h, E2h, F2h, 512, 512, 512);
    // 4. layer-1 aggregate: (rowtiles=64, heads=8, jzgrp=2) x 4 waves -> jz 0..7
    hipLaunchKernelGGL(gat_agg_k, dim3(64, 8, 2), dim3(256), 0, stream,
                       g1h, E2h, F2h, N, bits, VT1, Hpart, zpart, 512, 512, 8);
    // 5. finalize 1 -> hcatb
    hipLaunchKernelGGL(fin1_k, dim3(1024), dim3(256), 0, stream, Hpart, zpart, hcatb);
    // 6. gemm2 split-K=4 -> Cpart  (4-wave blocks)
    hipLaunchKernelGGL((gemm_k<0, 1>), dim3(64, 2, 4), dim3(256), 0, stream,
                       hcatb, WoutT, (bf16_t*)nullptr, Cpart,
                       (const float*)nullptr, (const float*)nullptr,
                       (float*)nullptr, (float*)nullptr, (float*)nullptr, 512, 128, 128);
    // 7. combine -> VT2, g1o/E2o/F2o
    hipLaunchKernelGGL(comb2_k, dim3(4096), dim3(128), 0, stream, Cpart, a1o, a2o, VT2, g1o, E2o, F2o);
    // 8. layer-2 aggregate: (rowtiles=64, colgrps=2, jzgrp=4) x 4 waves -> jz 0..15
    hipLaunchKernelGGL(gat_agg_k, dim3(64, 2, 4), dim3(256), 0, stream,
                       g1o, E2o, F2o, 0, bits, VT2, Hpart, zpart, 128, 256, 1);
    // 9. finalize 2 -> out
    hipLaunchKernelGGL(fin2_k, dim3(256), dim3(256), 0, stream, Hpart, zpart, (float*)d_out);
}